// Round 8
// baseline (399.465 us; speedup 1.0000x reference)
//
#include <hip/hip_runtime.h>

typedef unsigned int u32;
typedef unsigned long long u64;

#define NIMG 8
#define RR 10000
#define KK 80
#define SROW 81            // scores/logits row stride (K+1)
#define MPRE 2048
#define NTOP 100
#define NELEM (RR*KK)      // 800000 per image
#define P0B 64             // compact-scan blocks per image
#define P0E ((NELEM + P0B - 1) / P0B)   // 12500 elements per block
#define BUFCAP 3328        // >= 158 rows * 19 cands max per block (softmax bound)
#define CAP2 65536         // compact-list capacity per image (fallback if exceeded)
#define CBASE 0xC07Fu      // min value of key>>48 for s in (0.05, 1.0]

// ---- workspace layout (bytes) ---- total 4,915,456 B (< proven 7,145,728)
#define OFF_STATE  0ull
#define ST_CCNT    0        // u32[8]
#define ST_CSEL    32       // u32[8]
#define OFF_CB     256ull
#define OFF_OB     (OFF_CB   + 8ull*MPRE*16)
#define OFF_AREA   (OFF_OB   + 8ull*MPRE*16)
#define OFF_SCORE  (OFF_AREA + 8ull*MPRE*4)
#define OFF_FLAT   (OFF_SCORE+ 8ull*MPRE*4)
#define OFF_SUP    (OFF_FLAT + 8ull*MPRE*4)     // 8*2048*32*8 = 4,194,304
// Compact candidate list ALIASES the suppression matrix: cand is fully consumed
// by k_ssd before k_iou writes sup (stream-ordered). 8*CAP2*8 = 4,194,304 exactly.
#define OFF_CAND   OFF_SUP

// Zero the 64-word state block (ccnt, csel).
__global__ void k_init(u32* ws32) {
    if (threadIdx.x < 64) ws32[threadIdx.x] = 0;
}

// Full scan -> compact candidate list per image.
// Two-phase: LDS buffer (block-local atomic), ONE global atomicAdd per block.
__global__ __launch_bounds__(256) void k_compact(const float* __restrict__ scores, char* wsb) {
    int img = blockIdx.x / P0B, blk = blockIdx.x % P0B;
    int tid = threadIdx.x;
    __shared__ u64 lbuf[BUFCAP];
    __shared__ u32 lcnt, lbase;
    if (tid == 0) lcnt = 0;
    __syncthreads();
    const float* S = scores + (size_t)img * RR * SROW;
    int e0 = blk * P0E;
    int e1 = e0 + P0E; if (e1 > NELEM) e1 = NELEM;
    for (int e = e0 + tid; e < e1; e += 256) {
        int r = e / KK, c = e - r * KK;
        float s = S[(size_t)r * SROW + c];
        if (s > 0.05f) {
            u64 key = ((u64)(~__float_as_uint(s)) << 32) | (u32)e;
            u32 p = atomicAdd(&lcnt, 1u);
            if (p < BUFCAP) lbuf[p] = key;
        }
    }
    __syncthreads();
    if (tid == 0) {
        u32 add = lcnt;
        if (lcnt > BUFCAP) add = CAP2 + 1;   // unreachable; forces fallback path
        lbase = add ? atomicAdd(&((u32*)(wsb + OFF_STATE + ST_CCNT))[img], add) : 0u;
    }
    __syncthreads();
    u32 n = (lcnt < (u32)BUFCAP) ? lcnt : (u32)BUFCAP;
    u32 base = lbase;
    u64* cand = (u64*)(wsb + OFF_CAND) + (size_t)img * CAP2;
    for (u32 i = tid; i < n; i += 256) {
        u32 pos = base + i;
        if (pos < CAP2) cand[pos] = lbuf[i];
    }
}

// Select exact top-2048 keys (radix-select K*), sort them (bitonic), decode.
// One block per image. Fallback: if ccnt > CAP2, passes re-read raw scores.
__global__ __launch_bounds__(1024) void k_ssd(const float* __restrict__ scores,
                                              const float* __restrict__ boxes, char* wsb) {
    int img = blockIdx.x; int tid = threadIdx.x;
    __shared__ u64 sk[MPRE];        // 16 KB
    __shared__ u32 h4[4 * 1024];    // 16 KB: pass-0 privatized hist / 8-bit hist
    __shared__ u32 sv[1024];        // scan buffer
    __shared__ u64 sP;
    __shared__ u32 sNeed;
    __shared__ u32 sScnt;
    u32 ccnt = ((const u32*)(wsb + OFF_STATE + ST_CCNT))[img];
    bool fb = ccnt > CAP2;
    u32 n = fb ? (u32)NELEM : ccnt;
    const u64* cand = (const u64*)(wsb + OFF_CAND) + (size_t)img * CAP2;
    const float* S = scores + (size_t)img * RR * SROW;
    if (tid == 0) sP = ~0ull;       // take-all default
    __syncthreads();

#define LOADKEY(idx, key, ok)                                              \
    do { if (fb) { u32 _e = (idx); u32 _r = _e / KK, _c = _e - _r * KK;    \
            float _s = S[(size_t)_r * SROW + _c]; (ok) = _s > 0.05f;       \
            (key) = (ok) ? (((u64)(~__float_as_uint(_s)) << 32) | _e) : 0; \
        } else { (key) = cand[idx]; (ok) = true; } } while (0)

    if (ccnt > MPRE) {
        // ---- pass 0: 1024 bins on (key>>48)-CBASE, 4-way privatized hist ----
        for (int b = tid; b < 4096; b += 1024) h4[b] = 0;
        __syncthreads();
        int wv = (tid >> 6) & 3;
        for (u32 idx0 = 0; idx0 < n; idx0 += 1024) {
            u32 idx = idx0 + tid;
            if (idx < n) {
                u64 key; bool ok; LOADKEY(idx, key, ok);
                if (ok) {
                    u32 cb = (u32)(key >> 48) - CBASE;
                    if (cb > 1023u) cb = 1023u;
                    atomicAdd(&h4[wv * 1024 + cb], 1u);
                }
            }
        }
        __syncthreads();
        u32 hb = h4[tid] + h4[1024 + tid] + h4[2048 + tid] + h4[3072 + tid];
        sv[tid] = hb;
        __syncthreads();
        for (int off = 1; off < 1024; off <<= 1) {
            u32 a = (tid >= off) ? sv[tid - off] : 0;
            __syncthreads();
            sv[tid] += a;
            __syncthreads();
        }
        {
            u32 incl = sv[tid], excl = incl - hb;
            u32 need = MPRE;
            if (excl < need && incl >= need) { sP = (u64)(CBASE + (u32)tid); sNeed = need - excl; }
        }
        __syncthreads();
        // ---- passes 1..6: 8-bit digits on bits [47:40] .. [7:0] ----
        for (int d = 1; d <= 6; ++d) {
            int shift = 48 - 8 * d;
            int csh = shift + 8;
            u64 P = sP; u32 nd = sNeed;
            __syncthreads();
            if (tid < 256) h4[tid] = 0;
            __syncthreads();
            for (u32 idx0 = 0; idx0 < n; idx0 += 1024) {
                u32 idx = idx0 + tid;
                if (idx < n) {
                    u64 key; bool ok; LOADKEY(idx, key, ok);
                    if (ok && (key >> csh) == P)
                        atomicAdd(&h4[(u32)(key >> shift) & 0xFFu], 1u);
                }
            }
            __syncthreads();
            u32 hbb = 0;
            if (tid < 256) { hbb = h4[tid]; sv[tid] = hbb; }
            __syncthreads();
            for (int off = 1; off < 256; off <<= 1) {
                u32 a = 0;
                if (tid < 256 && tid >= off) a = sv[tid - off];
                __syncthreads();
                if (tid < 256) sv[tid] += a;
                __syncthreads();
            }
            if (tid < 256) {
                u32 incl = sv[tid], excl = incl - hbb;
                if (excl < nd && incl >= nd) { sP = (P << 8) | (u32)tid; sNeed = nd - excl; }
            }
            __syncthreads();
        }
    }
    // ---- gather keys <= K* (exactly min(ccnt,2048): keys unique) ----
    if (tid == 0) sScnt = 0;
    for (int i = tid; i < MPRE; i += 1024) sk[i] = ~0ull;
    __syncthreads();
    u64 Ks = sP;
    int lane = tid & 63;
    for (u32 idx0 = 0; idx0 < n; idx0 += 1024) {
        u32 idx = idx0 + tid;
        u64 key = 0; bool ok = false;
        if (idx < n) LOADKEY(idx, key, ok);
        bool pred = ok && key <= Ks;
        u64 m = __ballot(pred);
        u32 cnt = (u32)__popcll(m);
        u32 base = 0;
        if (lane == 0 && cnt) base = atomicAdd(&sScnt, cnt);
        base = __shfl(base, 0);
        if (pred) {
            u32 pos = base + (u32)__popcll(m & ((1ull << lane) - 1ull));
            if (pos < MPRE) sk[pos] = key;
        }
    }
    __syncthreads();
    u32 scnt = sScnt; if (scnt > MPRE) scnt = MPRE;
    // ---- bitonic sort 2048 keys in LDS (ascending = score desc, idx asc) ----
    for (u32 k2 = 2; k2 <= MPRE; k2 <<= 1) {
        for (u32 j = k2 >> 1; j > 0; j >>= 1) {
            __syncthreads();
            for (int i = tid; i < MPRE; i += 1024) {
                int ixj = i ^ (int)j;
                if (ixj > i) {
                    u64 a = sk[i], b = sk[ixj];
                    bool up = ((i & (int)k2) == 0);
                    if ((a > b) == up) { sk[i] = b; sk[ixj] = a; }
                }
            }
        }
    }
    __syncthreads();
    // ---- decode: clip, class-offset boxes, areas ----
    float4* cb   = (float4*)(wsb + OFF_CB)   + (size_t)img * MPRE;
    float4* ob   = (float4*)(wsb + OFF_OB)   + (size_t)img * MPRE;
    float*  area = (float*)(wsb + OFF_AREA)  + (size_t)img * MPRE;
    float*  scv  = (float*)(wsb + OFF_SCORE) + (size_t)img * MPRE;
    u32*    flv  = (u32*)(wsb + OFF_FLAT)    + (size_t)img * MPRE;
    for (int i = tid; i < MPRE; i += 1024) {
        if (i < (int)scnt) {
            u64 key = sk[i];
            u32 e = (u32)key;
            u32 sbits = ~((u32)(key >> 32));
            float sc = __uint_as_float(sbits);
            u32 r = e / KK, c = e - r * KK;
            const float* bp = boxes + (((size_t)img * RR + r) * KK + c) * 4;
            float x1 = fminf(fmaxf(bp[0], 0.0f), 1333.0f);
            float y1 = fminf(fmaxf(bp[1], 0.0f), 800.0f);
            float x2 = fminf(fmaxf(bp[2], 0.0f), 1333.0f);
            float y2 = fminf(fmaxf(bp[3], 0.0f), 800.0f);
            float coff = (float)c * 4096.0f;
            float ox1 = __fadd_rn(x1, coff), oy1 = __fadd_rn(y1, coff);
            float ox2 = __fadd_rn(x2, coff), oy2 = __fadd_rn(y2, coff);
            float ar = __fmul_rn(fmaxf(__fsub_rn(ox2, ox1), 0.0f),
                                 fmaxf(__fsub_rn(oy2, oy1), 0.0f));
            cb[i] = make_float4(x1, y1, x2, y2);
            ob[i] = make_float4(ox1, oy1, ox2, oy2);
            area[i] = ar; scv[i] = sc; flv[i] = e;
        } else {
            cb[i] = make_float4(0.f, 0.f, 0.f, 0.f);
            ob[i] = make_float4(0.f, 0.f, 0.f, 0.f);
            area[i] = 0.f; scv[i] = 0.f; flv[i] = 0u;
        }
    }
    if (tid == 0) ((u32*)(wsb + OFF_STATE + ST_CSEL))[img] = scnt;
#undef LOADKEY
}

// 8 rows per 512-thread block (one wave per row); box table staged once in LDS.
// IoU vs all 2048 columns -> 32 u64 ballot words, j>i baked in.
__global__ __launch_bounds__(512) void k_iou(char* wsb) {
    int blk = blockIdx.x;                 // 2048 blocks
    int img = blk >> 8; int row0 = (blk & 255) * 8;
    int tid = threadIdx.x;
    __shared__ float4 sob[MPRE];
    __shared__ float  sarea[MPRE];
    const float4* ob   = (const float4*)(wsb + OFF_OB)  + (size_t)img * MPRE;
    const float*  area = (const float*)(wsb + OFF_AREA) + (size_t)img * MPRE;
    for (int i = tid; i < MPRE; i += 512) { sob[i] = ob[i]; sarea[i] = area[i]; }
    __syncthreads();
    int wid = tid >> 6, lane = tid & 63;
    int i = row0 + wid;
    float4 bi = sob[i]; float ai = sarea[i];
    u64* row = (u64*)(wsb + OFF_SUP) + ((size_t)img * MPRE + i) * 32;
    for (int ch = 0; ch < 32; ++ch) {
        int j = ch * 64 + lane;
        float4 bj = sob[j]; float aj = sarea[j];
        float ltx = fmaxf(bi.x, bj.x), lty = fmaxf(bi.y, bj.y);
        float rbx = fminf(bi.z, bj.z), rby = fminf(bi.w, bj.w);
        float w = fmaxf(__fsub_rn(rbx, ltx), 0.0f);
        float h = fmaxf(__fsub_rn(rby, lty), 0.0f);
        float inter = __fmul_rn(w, h);
        float den = __fadd_rn(__fsub_rn(__fadd_rn(ai, aj), inter), 1e-9f);
        float iou = inter / den;
        bool pred = (iou > 0.5f) && (j > i);
        u64 m = __ballot(pred);
        if (lane == 0) row[ch] = m;
    }
}

// Fused NMS + output. Wave 0 runs the serial NMS (register-only chain, early
// exit at 100 keeps); keep-mask passes via LDS; all 256 threads emit output.
__global__ __launch_bounds__(256) void k_nms_out(const float* __restrict__ logits,
                                                 char* wsb, float* __restrict__ out) {
    int img = blockIdx.x; int tid = threadIdx.x;
    __shared__ u64 kw[32];
    __shared__ u32 kpre[33];
    __shared__ int sel[NTOP];
    __shared__ int snk;
    int csel = (int)((const u32*)(wsb + OFF_STATE + ST_CSEL))[img];
    if (tid < 64) {
        int lane = tid;
        const u64* Sp = (const u64*)(wsb + OFF_SUP) + (size_t)img * MPRE * 32;
        u64 supw = 0;      // lanes 0..31: suppression word #lane
        u64 bcur = 0;      // all lanes: current word (i>>6), kept lane-uniform
        int kcnt = 0;
        bool doneF = false;
        const int D = 16;
        u64 pre[D]; u64 preb[D];
#pragma unroll
        for (int d = 0; d < D; ++d) {
            pre[d]  = (lane < 32 && d < csel) ? Sp[(size_t)d * 32 + lane] : 0ull;
            preb[d] = (d < csel) ? Sp[(size_t)d * 32 + 0] : 0ull;
        }
        for (int base = 0; base < csel && !doneF; base += D) {
            int w = base >> 6;
            if ((base & 63) == 0) bcur = __shfl(supw, w);
            int wn = (base + D) >> 6;
#pragma unroll
            for (int d = 0; d < D; ++d) {
                int i = base + d;
                u64 rowl = pre[d]; u64 rowb = preb[d];
                int ip = i + D;
                pre[d]  = (lane < 32 && ip < csel) ? Sp[(size_t)ip * 32 + lane] : 0ull;
                preb[d] = (ip < csel) ? Sp[(size_t)ip * 32 + wn] : 0ull;
                if (i < csel && !doneF) {
                    bool kept = !((bcur >> (i & 63)) & 1ull);
                    if (kept) {
                        if (lane < 32) supw |= rowl;
                        bcur |= rowb;
                        if (++kcnt >= NTOP) doneF = true;
                    }
                }
            }
        }
        if (lane < 32) {
            int b = lane << 6; u64 vw;
            if (csel >= b + 64) vw = ~0ull;
            else if (csel <= b) vw = 0ull;
            else vw = (1ull << (csel - b)) - 1ull;
            kw[lane] = vw & ~supw;
        }
    }
    __syncthreads();
    if (tid == 0) {
        u32 cum = 0;
        for (int w = 0; w < 32; ++w) { kpre[w] = cum; cum += (u32)__popcll(kw[w]); }
        kpre[32] = cum;
        snk = (cum < NTOP) ? (int)cum : NTOP;
    }
    __syncthreads();
    for (int i = tid; i < MPRE; i += 256) {
        u64 w = kw[i >> 6];
        if ((w >> (i & 63)) & 1ull) {
            u32 rank = kpre[i >> 6] + (u32)__popcll(w & ((1ull << (i & 63)) - 1ull));
            if (rank < NTOP) sel[rank] = i;
        }
    }
    __syncthreads();
    int nk = snk;
    const float4* cb  = (const float4*)(wsb + OFF_CB)   + (size_t)img * MPRE;
    const float*  scv = (const float*)(wsb + OFF_SCORE) + (size_t)img * MPRE;
    const u32*    flv = (const u32*)(wsb + OFF_FLAT)    + (size_t)img * MPRE;
    for (int idx = tid; idx < NTOP * 85; idx += 256) {
        int row = idx / 85, col = idx - row * 85;
        float v = 0.0f;
        if (row < nk) {
            int i = sel[row];
            if (col < 4) {
                float4 b = cb[i];
                v = (col == 0) ? b.x : (col == 1) ? b.y : (col == 2) ? b.z : b.w;
            } else if (col == 4) {
                v = scv[i];
            } else {
                u32 e = flv[i]; u32 r = e / KK;
                v = logits[((size_t)img * RR + r) * SROW + (u32)(col - 5)];
            }
        }
        out[(size_t)img * (NTOP * 85) + idx] = v;
    }
}

extern "C" void kernel_launch(void* const* d_in, const int* in_sizes, int n_in,
                              void* d_out, int out_size, void* d_ws, size_t ws_size,
                              hipStream_t stream) {
    const float* boxes  = (const float*)d_in[0];
    const float* scores = (const float*)d_in[1];
    const float* logits = (const float*)d_in[2];
    float* out = (float*)d_out;
    char* wsb = (char*)d_ws;

    k_init<<<1, 64, 0, stream>>>((u32*)d_ws);
    k_compact<<<NIMG * P0B, 256, 0, stream>>>(scores, wsb);
    k_ssd<<<NIMG, 1024, 0, stream>>>(scores, boxes, wsb);
    k_iou<<<NIMG * 256, 512, 0, stream>>>(wsb);
    k_nms_out<<<NIMG, 256, 0, stream>>>(logits, wsb, out);
}